// Round 9
// baseline (1017.564 us; speedup 1.0000x reference)
//
#include <hip/hip_runtime.h>
#include <stdint.h>

// ---------------- problem constants ----------------
#define B_SZ   256
#define SEQ_LEN 128
#define DIN    1024
#define DHID   2048
#define NCLS   1024
#define NBLK   256   // persistent grid = #CUs
#define NROUND 8     // 16-step blocking: h_15, h_31, ..., h_127

typedef unsigned short ushort_t;
typedef short bf16x8 __attribute__((ext_vector_type(8)));
typedef float f32x16 __attribute__((ext_vector_type(16)));
typedef ushort_t u16x8 __attribute__((ext_vector_type(8)));

__device__ __forceinline__ ushort_t f32_to_bf16(float f) {
  uint32_t u = __builtin_bit_cast(uint32_t, f);
  u = (u + 0x7FFFu + ((u >> 16) & 1u)) >> 16;
  return (ushort_t)u;
}
__device__ __forceinline__ float bf16_to_f32(ushort_t h) {
  uint32_t u = ((uint32_t)h) << 16;
  return __builtin_bit_cast(float, u);
}

// async global->LDS, 16B per lane (cached path)
__device__ __forceinline__ void llds16(const ushort_t* g, ushort_t* l) {
  __builtin_amdgcn_global_load_lds(
      (const __attribute__((address_space(1))) void*)g,
      (__attribute__((address_space(3))) void*)l, 16, 0, 0);
}

__device__ __forceinline__ void cstore_f32(float* p, float v) {
  __hip_atomic_store(p, v, __ATOMIC_RELAXED, __HIP_MEMORY_SCOPE_AGENT);
}
__device__ __forceinline__ void cstore_u64(void* p, uint64_t v) {
  __hip_atomic_store((uint64_t*)p, v, __ATOMIC_RELAXED, __HIP_MEMORY_SCOPE_AGENT);
}
__device__ __forceinline__ uint64_t cload_u64(const void* p) {
  return __hip_atomic_load((const uint64_t*)p, __ATOMIC_RELAXED, __HIP_MEMORY_SCOPE_AGENT);
}
__device__ __forceinline__ void cstore_u32(unsigned* p, unsigned v) {
  __hip_atomic_store(p, v, __ATOMIC_RELAXED, __HIP_MEMORY_SCOPE_AGENT);
}
__device__ __forceinline__ unsigned cload_u32(const unsigned* p) {
  return __hip_atomic_load(p, __ATOMIC_RELAXED, __HIP_MEMORY_SCOPE_AGENT);
}

// contention-free grid barrier: per-block flag STORE (no RMW serialization),
// wave0 polls all 256 flags (4 per lane), ballot-all.
__device__ __forceinline__ void gsync(unsigned* flags, unsigned ep) {
  __syncthreads();
  if (threadIdx.x == 0) cstore_u32(&flags[blockIdx.x], ep);
  if (threadIdx.x < 64) {
    const unsigned* f = flags + threadIdx.x * 4;
    for (;;) {
      unsigned a = cload_u32(f + 0), b = cload_u32(f + 1);
      unsigned c = cload_u32(f + 2), d = cload_u32(f + 3);
      bool ok = (a >= ep) & (b >= ep) & (c >= ep) & (d >= ep);
      if (__ballot(ok) == ~0ull) break;
      __builtin_amdgcn_s_sleep(1);
    }
  }
  __syncthreads();
}

// ---------------- fused conversion / transpose kernels ----------------
// Whh f32 -> {hi, lo, hiT, loT} in ONE pass.
__global__ void k_splitT(const float* __restrict__ src, ushort_t* __restrict__ hi,
                         ushort_t* __restrict__ lo, ushort_t* __restrict__ hiT,
                         ushort_t* __restrict__ loT) {
  __shared__ ushort_t th[64][65];
  __shared__ ushort_t tl[64][65];
  const int bx = blockIdx.x * 64, by = blockIdx.y * 64;
  const int c = threadIdx.x & 63, r0 = (threadIdx.x >> 6) * 16;
#pragma unroll
  for (int i = 0; i < 16; ++i) {
    size_t o = (size_t)(by + r0 + i) * DHID + bx + c;
    float v = src[o];
    ushort_t hh = f32_to_bf16(v);
    ushort_t ll = f32_to_bf16(v - bf16_to_f32(hh));
    hi[o] = hh;
    lo[o] = ll;
    th[r0 + i][c] = hh;
    tl[r0 + i][c] = ll;
  }
  __syncthreads();
#pragma unroll
  for (int i = 0; i < 16; ++i) {
    size_t o = (size_t)(bx + r0 + i) * DHID + by + c;
    hiT[o] = th[c][r0 + i];
    loT[o] = tl[c][r0 + i];
  }
}

// paired bf16 2048x2048 transpose: two matrices per launch
__global__ void k_trb2(const ushort_t* __restrict__ sA, ushort_t* __restrict__ dA,
                       const ushort_t* __restrict__ sB, ushort_t* __restrict__ dB) {
  __shared__ ushort_t ta[64][65];
  __shared__ ushort_t tb[64][65];
  const int bx = blockIdx.x * 64, by = blockIdx.y * 64;
  const int c = threadIdx.x & 63, r0 = (threadIdx.x >> 6) * 16;
#pragma unroll
  for (int i = 0; i < 16; ++i) {
    size_t o = (size_t)(by + r0 + i) * DHID + bx + c;
    ta[r0 + i][c] = sA[o];
    tb[r0 + i][c] = sB[o];
  }
  __syncthreads();
#pragma unroll
  for (int i = 0; i < 16; ++i) {
    size_t o = (size_t)(bx + r0 + i) * DHID + by + c;
    dA[o] = ta[c][r0 + i];
    dB[o] = tb[c][r0 + i];
  }
}

// Whx f32 [DHID][DIN] -> bf16 d [DHID][DIN] + dT [DIN][DHID]
__global__ void k_cvtW(const float* __restrict__ src, ushort_t* __restrict__ d,
                       ushort_t* __restrict__ dT) {
  __shared__ ushort_t t[64][65];
  const int bx = blockIdx.x * 64, by = blockIdx.y * 64;
  const int c = threadIdx.x & 63, r0 = (threadIdx.x >> 6) * 16;
#pragma unroll
  for (int i = 0; i < 16; ++i) {
    size_t o = (size_t)(by + r0 + i) * DIN + bx + c;
    ushort_t hh = f32_to_bf16(src[o]);
    d[o] = hh;
    t[r0 + i][c] = hh;
  }
  __syncthreads();
#pragma unroll
  for (int i = 0; i < 16; ++i)
    dT[(size_t)(bx + r0 + i) * DHID + by + c] = t[c][r0 + i];
}

__global__ void k_cvt(const float* __restrict__ s, ushort_t* __restrict__ d, int n4) {
  int i = blockIdx.x * 256 + threadIdx.x;
  if (i >= n4) return;
  float4 v = ((const float4*)s)[i];
  ushort4 hv;
  hv.x = f32_to_bf16(v.x); hv.y = f32_to_bf16(v.y);
  hv.z = f32_to_bf16(v.z); hv.w = f32_to_bf16(v.w);
  ((ushort4*)d)[i] = hv;
}

// fused f32->bf16 convert + [B][S][D] -> [S][B][D] time-major transpose.
__global__ void k_cvtT(const float* __restrict__ s, ushort_t* __restrict__ d) {
  int i = blockIdx.x * 256 + threadIdx.x;      // over B*S*D/8
  int dd = (i & (DIN / 8 - 1)) * 8;
  int bs = i >> 7;                             // b*SEQ_LEN + t
  int b = bs >> 7;                             // /SEQ_LEN
  int t = bs & (SEQ_LEN - 1);
  const float* src = s + (size_t)bs * DIN + dd;
  float4 v0 = *(const float4*)src;
  float4 v1 = *(const float4*)(src + 4);
  u16x8 hv;
  hv[0] = f32_to_bf16(v0.x); hv[1] = f32_to_bf16(v0.y);
  hv[2] = f32_to_bf16(v0.z); hv[3] = f32_to_bf16(v0.w);
  hv[4] = f32_to_bf16(v1.x); hv[5] = f32_to_bf16(v1.y);
  hv[6] = f32_to_bf16(v1.z); hv[7] = f32_to_bf16(v1.w);
  *(u16x8*)(d + ((size_t)t * B_SZ + b) * DIN + dd) = hv;
}

// b2[h] = b[h] + sum_j W[h,j] b[j]  (f32, one wave per row)
__global__ void k_bvec(const float* __restrict__ W, const float* __restrict__ b,
                       float* __restrict__ out) {
  int row = (blockIdx.x * blockDim.x + threadIdx.x) >> 6;
  int lane = threadIdx.x & 63;
  if (row >= DHID) return;
  float s = 0.0f;
  for (int j = lane; j < DHID; j += 64) s += W[(size_t)row * DHID + j] * b[j];
#pragma unroll
  for (int off = 32; off; off >>= 1) s += __shfl_down(s, off);
  if (lane == 0) out[row] = b[row] + s;
}

// ---------------- generic 128x128-tile GEMM, two cores ----------
// C[M,N] = sum_seg A_seg * B_seg^T (+bias[col] | +bf16 D), out bf16,
// optional hi/lo split. A row r -> element offset (r>>8)*tA + (r&255)*sA.
// B is [N, klen] row-major. Flat grid, NATURAL launch order (no XCD swizzle).
// NOTE (R6): do NOT fuse a transposed-output pass into the epilogue (regalloc
// collapse -> scratch spills). NOTE (R8): 256^2 4-phase counted-vmcnt core was
// NEUTRAL (same 29% MfmaUtil) — the ~660-690 TF ceiling is not schedule-bound
// at this tile size; keep the simple validated cores.
struct BigArgs {
  const ushort_t* A[3];
  const ushort_t* B[3];
  int nseg;
  int klen;
  size_t tA, sA;
  size_t ldo;          // output row stride (elements)
  const ushort_t* D;   // bf16 D or null; row map (r>>8)*tD + (r&255)*2048
  size_t tD;
  const float* bias;   // or null
  ushort_t* out_hi;
  ushort_t* out_lo;    // or null
  int lognx;           // log2(N/128)
};

// epilogue shared by both cores (validated R1-R5 codegen)
__device__ __forceinline__ void big_epi(const BigArgs& a, f32x16 (&acc)[2][2],
                                        int bm0, int bn0) {
  const int tid = threadIdx.x, lane = tid & 63, wv = tid >> 6;
  const int l31 = lane & 31, half = lane >> 5;
  int gm0 = bm0 + (wv & 1) * 64, gn0 = bn0 + (wv >> 1) * 64;
#pragma unroll
  for (int mi = 0; mi < 2; ++mi)
#pragma unroll
    for (int ni = 0; ni < 2; ++ni)
#pragma unroll
      for (int r = 0; r < 16; ++r) {
        int row = gm0 + mi * 32 + (r & 3) + 8 * (r >> 2) + 4 * half;
        int col = gn0 + ni * 32 + l31;
        float v = acc[mi][ni][r];
        if (a.bias) v += a.bias[col];
        if (a.D)
          v += bf16_to_f32(a.D[(size_t)(row >> 8) * a.tD +
                               (size_t)(row & 255) * 2048 + col]);
        ushort_t hh = f32_to_bf16(v);
        a.out_hi[(size_t)row * a.ldo + col] = hh;
        if (a.out_lo)
          a.out_lo[(size_t)row * a.ldo + col] = f32_to_bf16(v - bf16_to_f32(hh));
      }
}

// ---- dbuf core (validated R1/R4) ----
__device__ __forceinline__ void big_body_db(const BigArgs& a, int wg) {
  __shared__ __align__(16) ushort_t lds[32768];  // 64KB
  const int tid = threadIdx.x, lane = tid & 63, wv = tid >> 6;
  const int l31 = lane & 31, half = lane >> 5;

  const int bn0 = (wg & ((1 << a.lognx) - 1)) * 128;
  const int bm0 = (wg >> a.lognx) * 128;
  const int t_ = bm0 >> 8, mrem = bm0 & 255;
  const int kit = a.klen >> 6;

  f32x16 acc[2][2];
#pragma unroll
  for (int p = 0; p < 2; ++p)
#pragma unroll
    for (int q = 0; q < 2; ++q)
#pragma unroll
      for (int r = 0; r < 16; ++r) acc[p][q][r] = 0.0f;

  auto stage = [&](int buf, int i) {
    int seg = 0, ii = i;
    while (ii >= kit) { ii -= kit; ++seg; }
    const int kc = ii * 64;
    const ushort_t* Ab = a.A[seg];
    const ushort_t* Bb = a.B[seg];
#pragma unroll
    for (int j = 0; j < 4; ++j) {
      int s = tid + 256 * j;
      int prow = s >> 3, glc = (s & 7) ^ (prow & 7);
      llds16(Ab + (size_t)t_ * a.tA + (size_t)(mrem + prow) * a.sA + (kc + glc * 8),
             &lds[(size_t)(buf * 16384 + (wv * 64 + 256 * j) * 16) / 2]);
      llds16(Bb + (size_t)(bn0 + prow) * a.klen + (kc + glc * 8),
             &lds[(size_t)(32768 + buf * 16384 + (wv * 64 + 256 * j) * 16) / 2]);
    }
  };

  const int nit = a.nseg * kit;
  stage(0, 0);
  for (int i = 0; i < nit; ++i) {
    int buf = i & 1;
    if (i + 1 < nit) {
      stage(buf ^ 1, i + 1);
      __builtin_amdgcn_s_waitcnt(0x3FF0 | 8);
    } else {
      __builtin_amdgcn_s_waitcnt(0x3FF0);
    }
    __builtin_amdgcn_s_barrier();
    const ushort_t* At = &lds[buf * 8192];
    const ushort_t* Bt = &lds[16384 + buf * 8192];
#pragma unroll
    for (int ks = 0; ks < 4; ++ks) {
      int ch = ks * 2 + half;
      bf16x8 af[2], bf_[2];
#pragma unroll
      for (int mi = 0; mi < 2; ++mi) {
        int row = (wv & 1) * 64 + mi * 32 + l31;
        int pch = ch ^ (row & 7);
        af[mi] = *(const bf16x8*)&At[row * 64 + pch * 8];
      }
#pragma unroll
      for (int ni = 0; ni < 2; ++ni) {
        int row = (wv >> 1) * 64 + ni * 32 + l31;
        int pch = ch ^ (row & 7);
        bf_[ni] = *(const bf16x8*)&Bt[row * 64 + pch * 8];
      }
#pragma unroll
      for (int mi = 0; mi < 2; ++mi)
#pragma unroll
        for (int ni = 0; ni < 2; ++ni)
          acc[mi][ni] = __builtin_amdgcn_mfma_f32_32x32x16_bf16(
              af[mi], bf_[ni], acc[mi][ni], 0, 0, 0);
    }
    __builtin_amdgcn_s_barrier();
  }
  big_epi(a, acc, bm0, bn0);
}

// ---- m97 single-buffer core (validated R2) ----
__device__ __forceinline__ void big_body_sb(const BigArgs& a, int wg) {
  __shared__ __align__(16) ushort_t lds[16384];  // 32KB
  const int tid = threadIdx.x, lane = tid & 63, wv = tid >> 6;
  const int l31 = lane & 31, half = lane >> 5;

  const int bn0 = (wg & ((1 << a.lognx) - 1)) * 128;
  const int bm0 = (wg >> a.lognx) * 128;
  const int t_ = bm0 >> 8, mrem = bm0 & 255;
  const int kit = a.klen >> 6;

  f32x16 acc[2][2];
#pragma unroll
  for (int p = 0; p < 2; ++p)
#pragma unroll
    for (int q = 0; q < 2; ++q)
#pragma unroll
      for (int r = 0; r < 16; ++r) acc[p][q][r] = 0.0f;

  auto stage = [&](int i) {
    int seg = 0, ii = i;
    while (ii >= kit) { ii -= kit; ++seg; }
    const int kc = ii * 64;
    const ushort_t* Ab = a.A[seg];
    const ushort_t* Bb = a.B[seg];
#pragma unroll
    for (int j = 0; j < 4; ++j) {
      int s = tid + 256 * j;
      int prow = s >> 3, glc = (s & 7) ^ (prow & 7);
      llds16(Ab + (size_t)t_ * a.tA + (size_t)(mrem + prow) * a.sA + (kc + glc * 8),
             &lds[(size_t)((wv * 64 + 256 * j) * 16) / 2]);
      llds16(Bb + (size_t)(bn0 + prow) * a.klen + (kc + glc * 8),
             &lds[(size_t)(16384 + (wv * 64 + 256 * j) * 16) / 2]);
    }
  };

  const int nit = a.nseg * kit;
  for (int i = 0; i < nit; ++i) {
    stage(i);
    __builtin_amdgcn_s_waitcnt(0x3FF0);
    __builtin_amdgcn_s_barrier();
    const ushort_t* At = &lds[0];
    const ushort_t* Bt = &lds[8192];
#pragma unroll
    for (int ks = 0; ks < 4; ++ks) {
      int ch = ks * 2 + half;
      bf16x8 af[2], bf_[2];
#pragma unroll
      for (int mi = 0; mi < 2; ++mi) {
        int row = (wv & 1) * 64 + mi * 32 + l31;
        int pch = ch ^ (row & 7);
        af[mi] = *(const bf16x8*)&At[row * 64 + pch * 8];
      }
#pragma unroll
      for (int ni = 0; ni < 2; ++ni) {
        int row = (wv >> 1) * 64 + ni * 32 + l31;
        int pch = ch ^ (row & 7);
        bf_[ni] = *(const bf16x8*)&Bt[row * 64 + pch * 8];
      }
#pragma unroll
      for (int mi = 0; mi < 2; ++mi)
#pragma unroll
        for (int ni = 0; ni < 2; ++ni)
          acc[mi][ni] = __builtin_amdgcn_mfma_f32_32x32x16_bf16(
              af[mi], bf_[ni], acc[mi][ni], 0, 0, 0);
    }
    __builtin_amdgcn_s_barrier();
  }
  big_epi(a, acc, bm0, bn0);
}

// dbuf wrappers (<=2 blocks/CU dispatches)
__global__ __launch_bounds__(256, 1) void k_big1(BigArgs a) {
  big_body_db(a, blockIdx.x);
}
__global__ __launch_bounds__(256, 1) void k_big2(BigArgs a0, BigArgs a1, int nblk0) {
  int wg = blockIdx.x;
  if (wg < nblk0) {
    big_body_db(a0, wg);
  } else {
    big_body_db(a1, wg - nblk0);
  }
}

// single-buffer wrappers (>=3 blocks/CU dispatches)
__global__ __launch_bounds__(256, 4) void k_big1s(BigArgs a) {
  big_body_sb(a, blockIdx.x);
}
__global__ __launch_bounds__(256, 4) void k_big2s(BigArgs a0, BigArgs a1, int nblk0) {
  int wg = blockIdx.x;
  if (wg < nblk0) {
    big_body_sb(a0, wg);
  } else {
    big_body_sb(a1, wg - nblk0);
  }
}

// ---------------- persistent recurrence kernel (512 threads, 8 waves) -------
__global__ __launch_bounds__(512, 2) void k_rnn(
    const ushort_t* __restrict__ w_hi, const ushort_t* __restrict__ w_lo,
    ushort_t* __restrict__ h_hi, ushort_t* __restrict__ h_lo,
    const ushort_t* __restrict__ z_hi, const ushort_t* __restrict__ z_lo,
    float* __restrict__ P, unsigned* __restrict__ flags) {
  __shared__ __align__(16) ushort_t lds[81920];  // 160 KiB
  char* ldsb = (char*)&lds[0];

  const int tid = threadIdx.x, lane = tid & 63, wv = tid >> 6;
  const int l31 = lane & 31, half = lane >> 5;
  const int kslice = wv & 1, mq = (wv >> 1) & 1, nq = wv >> 2;
  const int b = blockIdx.x;
  const int kb = b & 7, nb = (b >> 3) & 15, mb = b >> 7;
  const int n0 = nb * 128, k0 = kb * 256, m0 = mb * 128;

  // ---- pin W16 slices in LDS (once; cached path) ----
#pragma unroll
  for (int hl = 0; hl < 2; ++hl) {
    const ushort_t* W = hl ? w_lo : w_hi;
    for (int p = 0; p < 4; ++p)
#pragma unroll
      for (int j = 0; j < 2; ++j) {
        int s = tid + 512 * j;
        int prow = s >> 3, glc = (s & 7) ^ (prow & 7);
        const ushort_t* g = W + (size_t)(n0 + prow) * DHID + (k0 + p * 64 + glc * 8);
        ushort_t* d = (ushort_t*)(ldsb + hl * 65536 + p * 16384 + (wv * 64 + 512 * j) * 16);
        llds16(g, d);
      }
  }
  __builtin_amdgcn_s_waitcnt(0x3FF0);
  __syncthreads();

  const int srow0 = wv * 16 + (lane >> 4);
  const int skk   = 4 * (lane & 15);
  const int sg    = (lane & 15) >> 1;
  const int ssub  = lane & 1;

  uint64_t R[4][4];

  auto regload = [&](int slot, int c) {
    const ushort_t* src = (c < 4) ? h_hi : h_lo;
    const int p = c & 3;
#pragma unroll
    for (int i = 0; i < 4; ++i)
      R[slot][i] = cload_u64(src + (size_t)(m0 + srow0 + 4 * i) * DHID +
                             (k0 + p * 64 + skk));
  };
  auto dswrite = [&](int buf, int slot) {
#pragma unroll
    for (int i = 0; i < 4; ++i) {
      int lr = srow0 + 4 * i;
      *(uint64_t*)(ldsb + 131072 + buf * 16384 + lr * 128 +
                   ((sg ^ (lr & 7)) * 16) + ssub * 8) = R[slot][i];
    }
  };

  auto phaseB = [&](ushort4 zq, ushort4 zl, bool withP) {
    const int r = b;
    const int c0 = tid * 4;
    float v[4] = {bf16_to_f32(zq.x) + bf16_to_f32(zl.x),
                  bf16_to_f32(zq.y) + bf16_to_f32(zl.y),
                  bf16_to_f32(zq.z) + bf16_to_f32(zl.z),
                  bf16_to_f32(zq.w) + bf16_to_f32(zl.w)};
    if (withP) {
#pragma unroll
      for (int k = 0; k < 8; ++k) {
        const float* pp = P + ((size_t)k * B_SZ + r) * DHID + c0;
#pragma unroll
        for (int j = 0; j < 2; ++j) {
          uint64_t q = cload_u64((const uint64_t*)pp + j);
          float2 f = __builtin_bit_cast(float2, q);
          v[2 * j]     += f.x;
          v[2 * j + 1] += f.y;
        }
      }
    }
    ushort_t hh[4], ll[4];
#pragma unroll
    for (int e = 0; e < 4; ++e) {
      hh[e] = f32_to_bf16(v[e]);
      ll[e] = f32_to_bf16(v[e] - bf16_to_f32(hh[e]));
    }
    uint64_t q0, q1;
    __builtin_memcpy(&q0, &hh[0], 8);
    __builtin_memcpy(&q1, &ll[0], 8);
    cstore_u64(h_hi + (size_t)r * DHID + c0, q0);
    cstore_u64(h_lo + (size_t)r * DHID + c0, q1);
  };

  unsigned ep = 1;
  {
    ushort4 zq = *(const ushort4*)(z_hi + (size_t)b * DHID + tid * 4);
    ushort4 zl = *(const ushort4*)(z_lo + (size_t)b * DHID + tid * 4);
    phaseB(zq, zl, false);  // h_15 = z16[0]
  }
  gsync(flags, ep); ++ep;

  for (int j = 1; j < NROUND; ++j) {
    f32x16 acc[2][2];
#pragma unroll
    for (int p = 0; p < 2; ++p)
#pragma unroll
      for (int q = 0; q < 2; ++q)
#pragma unroll
        for (int r = 0; r < 16; ++r) acc[p][q][r] = 0.0f;

    regload(0, 0); regload(1, 1); regload(2, 2); regload(3, 3);
    dswrite(0, 0);
    __syncthreads();

    for (int c = 0; c < 8; ++c) {
      if (c + 4 <= 7) regload(c & 3, c + 4);
      if (c + 1 <= 7) dswrite((c + 1) & 1, (c + 1) & 3);

      const char* At = ldsb + 131072 + (c & 1) * 16384;
      const char* Bh = ldsb + (size_t)(c & 3) * 16384;
      const char* Bl = ldsb + 65536 + (size_t)(c & 3) * 16384;
      const bool isHi = c < 4;
#pragma unroll
      for (int ks = 0; ks < 2; ++ks) {
        const int g = (kslice * 2 + ks) * 2 + half;
        bf16x8 af[2], bh_[2], bl_[2];
#pragma unroll
        for (int mi = 0; mi < 2; ++mi) {
          int row = mq * 64 + mi * 32 + l31;
          af[mi] = *(const bf16x8*)(At + row * 128 + (g ^ (row & 7)) * 16);
        }
#pragma unroll
        for (int ni = 0; ni < 2; ++ni) {
          int row = nq * 64 + ni * 32 + l31;
          int off = row * 128 + (g ^ (row & 7)) * 16;
          bh_[ni] = *(const bf16x8*)(Bh + off);
          if (isHi) bl_[ni] = *(const bf16x8*)(Bl + off);
        }
#pragma unroll
        for (int mi = 0; mi < 2; ++mi)
#pragma unroll
          for (int ni = 0; ni < 2; ++ni) {
            acc[mi][ni] = __builtin_amdgcn_mfma_f32_32x32x16_bf16(
                af[mi], bh_[ni], acc[mi][ni], 0, 0, 0);
            if (isHi)
              acc[mi][ni] = __builtin_amdgcn_mfma_f32_32x32x16_bf16(
                  af[mi], bl_[ni], acc[mi][ni], 0, 0, 0);
          }
      }
      __syncthreads();
    }

    // ---- reduce kslice pairs through LDS ----
    {
      float* scr = (float*)(ldsb + 131072);
      const int pr = mq * 2 + nq;
#pragma unroll
      for (int r = 0; r < 2; ++r) {
        if (kslice == 1) {
#pragma unroll
          for (int ni = 0; ni < 2; ++ni)
#pragma unroll
            for (int reg = 0; reg < 16; ++reg) {
              int row32 = (reg & 3) + 8 * (reg >> 2) + 4 * half;
              scr[pr * 2048 + row32 * 64 + ni * 32 + l31] = acc[r][ni][reg];
            }
        }
        __syncthreads();
        if (kslice == 0) {
#pragma unroll
          for (int ni = 0; ni < 2; ++ni)
#pragma unroll
            for (int reg = 0; reg < 16; ++reg) {
              int row32 = (reg & 3) + 8 * (reg >> 2) + 4 * half;
              acc[r][ni][reg] += scr[pr * 2048 + row32 * 64 + ni * 32 + l31];
            }
        }
        __syncthreads();
      }
    }

    if (kslice == 0) {
      float* Pt = P + (size_t)kb * (B_SZ * DHID);
#pragma unroll
      for (int mi = 0; mi < 2; ++mi)
#pragma unroll
        for (int ni = 0; ni < 2; ++ni)
#pragma unroll
          for (int reg = 0; reg < 16; ++reg) {
            int row = m0 + mq * 64 + mi * 32 + (reg & 3) + 8 * (reg >> 2) + 4 * half;
            int col = n0 + nq * 64 + ni * 32 + l31;
            cstore_f32(&Pt[(size_t)row * DHID + col], acc[mi][ni][reg]);
          }
    }
    ushort4 zq = *(const ushort4*)(z_hi + ((size_t)j * 256 + b) * DHID + tid * 4);
    ushort4 zl = *(const ushort4*)(z_lo + ((size_t)j * 256 + b) * DHID + tid * 4);
    gsync(flags, ep); ++ep;

    phaseB(zq, zl, true);
    gsync(flags, ep); ++ep;
  }
}

// ---------------- readout GEMM (validated R2 segmented kernel) -----------
struct Seg {
  const ushort_t* A;
  const ushort_t* B;
  int a_stride;
  int b_stride;
  int k_len;
};
struct Args {
  Seg seg[4];
  int n_seg;
  int n_iters;
  const float* bias;
  ushort_t* out_hi;
  ushort_t* out_lo;
  float* out_f32;
  int ldo;
};

#define DEPTH 6
__global__ __launch_bounds__(256, 1) void k_gemm(Args args) {
  __shared__ __align__(16) char pool[DEPTH * 12288];
  const int tid = threadIdx.x, lane = tid & 63, wv = tid >> 6;
  const int bm0 = blockIdx.y * 32, bn0 = blockIdx.x * 64;

  f32x16 acc[2];
#pragma unroll
  for (int c = 0; c < 2; ++c)
#pragma unroll
    for (int r = 0; r < 16; ++r) acc[c][r] = 0.0f;

  const int prow0 = tid >> 3;
  const int glc0 = (tid & 7) ^ (prow0 & 7);
  const int prow1 = (tid + 256) >> 3;
  const int glc1 = (tid & 7) ^ (prow1 & 7);

  auto stage = [&](int buf, const Seg& sg, int k0) {
    const ushort_t* ga = sg.A + (size_t)(bm0 + prow0) * sg.a_stride + (k0 + glc0 * 8);
    const ushort_t* gb0 = sg.B + (size_t)(bn0 + prow0) * sg.b_stride + (k0 + glc0 * 8);
    const ushort_t* gb1 = sg.B + (size_t)(bn0 + prow1) * sg.b_stride + (k0 + glc1 * 8);
    ushort_t* la = (ushort_t*)(pool + buf * 12288) + wv * 512;
    ushort_t* lb = (ushort_t*)(pool + buf * 12288 + 4096) + wv * 512;
    llds16(ga, la);
    llds16(gb0, lb);
    llds16(gb1, lb + 2048);
  };

  const int nit = args.n_iters;
  int sc = 0, kc = 0;
  int nst = nit < (DEPTH - 1) ? nit : (DEPTH - 1);
  for (int s = 0; s < nst; ++s) {
    stage(s, args.seg[sc], kc);
    kc += 64;
    if (kc >= args.seg[sc].k_len) { kc = 0; ++sc; }
  }

  const int half = lane >> 5, l31 = lane & 31;
  const int lch = wv * 2 + half;
  int sb = DEPTH - 1, cb = 0;

  for (int i = 0; i < nit; ++i) {
    int ahead = nit - 1 - i;
    if (ahead > DEPTH - 1) ahead = DEPTH - 1;
    if (i + DEPTH - 1 < nit) {
      stage(sb, args.seg[sc], kc);
      if (++sb == DEPTH) sb = 0;
      kc += 64;
      if (kc >= args.seg[sc].k_len) { kc = 0; ++sc; }
    }
    switch (ahead) {
      case 5: __builtin_amdgcn_s_waitcnt(0x3FF0 | 15); break;
      case 4: __builtin_amdgcn_s_waitcnt(0x3FF0 | 12); break;
      case 3: __builtin_amdgcn_s_waitcnt(0x3FF0 | 9); break;
      case 2: __builtin_amdgcn_s_waitcnt(0x3FF0 | 6); break;
      case 1: __builtin_amdgcn_s_waitcnt(0x3FF0 | 3); break;
      default: __builtin_amdgcn_s_waitcnt(0x3FF0 | 0); break;
    }
    __builtin_amdgcn_s_barrier();

    const ushort_t* tA = (const ushort_t*)(pool + cb * 12288);
    const ushort_t* tB = tA + 2048;
    bf16x8 af, bfm[2];
    {
      int row = l31;
      int pch = lch ^ (row & 7);
      af = *(const bf16x8*)&tA[row * 64 + pch * 8];
    }
#pragma unroll
    for (int ni = 0; ni < 2; ++ni) {
      int row = ni * 32 + l31;
      int pch = lch ^ (row & 7);
      bfm[ni] = *(const bf16x8*)&tB[row * 64 + pch * 8];
    }
#pragma unroll
    for (int ni = 0; ni < 2; ++ni)
      acc[ni] = __builtin_amdgcn_mfma_f32_32x32x16_bf16(af, bfm[ni], acc[ni], 0, 0, 0);

    if (++cb == DEPTH) cb = 0;
    __builtin_amdgcn_s_barrier();
  }

  __syncthreads();
  float* red = (float*)pool + wv * 2048;
#pragma unroll
  for (int ni = 0; ni < 2; ++ni)
#pragma unroll
    for (int r = 0; r < 16; ++r) {
      int row = (r & 3) + 8 * (r >> 2) + 4 * half;
      int col = ni * 32 + l31;
      red[row * 64 + col] = acc[ni][r];
    }
  __syncthreads();

  const float* r0 = (const float*)pool;
  const float* r1 = r0 + 2048;
  const float* r2 = r0 + 4096;
  const float* r3 = r0 + 6144;
#pragma unroll
  for (int j = 0; j < 8; ++j) {
    int e = j * 256 + tid;
    int row = e >> 6, col = e & 63;
    float v = r0[e] + r1[e] + r2[e] + r3[e] + args.bias[bn0 + col];
    size_t o = (size_t)(bm0 + row) * args.ldo + (bn0 + col);
    if (args.out_f32) {
      args.out_f32[o] = v;
    } else {
      ushort_t h = f32_to_bf16(v);
      args.out_hi[o] = h;
      args.out_lo[o] = f32_to_bf16(v - bf16_to_f32(h));
    }
  }
}

// ---------------- launch ----------------
extern "C" void kernel_launch(void* const* d_in, const int* in_sizes, int n_in,
                              void* d_out, int out_size, void* d_ws, size_t ws_size,
                              hipStream_t stream) {
  const float* x   = (const float*)d_in[0];
  const float* Whx = (const float*)d_in[1];
  const float* Whh = (const float*)d_in[2];
  const float* Wph = (const float*)d_in[3];
  const float* bh  = (const float*)d_in[4];
  const float* bp  = (const float*)d_in[5];

  const size_t WSZ = (size_t)DHID * DHID * 2;  // 8 MiB (one bf16 2048^2)
  char* p = (char*)d_ws;
  ushort_t* whh_hi = (ushort_t*)p; p += WSZ;
  ushort_t* whh_lo = (ushort_t*)p; p += WSZ;
  ushort_t* whhT_hi= (ushort_t*)p; p += WSZ;
  ushort_t* whhT_lo= (ushort_t*)p; p += WSZ;
  ushort_t* w2_hi  = (ushort_t*)p; p += WSZ;
  ushort_t* w2_lo  = (ushort_t*)p; p += WSZ;
  ushort_t* w2T_hi = (ushort_t*)p; p += WSZ;
  ushort_t* w2T_lo = (ushort_t*)p; p += WSZ;
  ushort_t* w4_hi  = (ushort_t*)p; p += WSZ;
  ushort_t* w4_lo  = (ushort_t*)p; p += WSZ;
  ushort_t* w4T_hi = (ushort_t*)p; p += WSZ;
  ushort_t* w4T_lo = (ushort_t*)p; p += WSZ;
  ushort_t* w8_hi  = (ushort_t*)p; p += WSZ;
  ushort_t* w8_lo  = (ushort_t*)p; p += WSZ;
  ushort_t* w8T_hi = (ushort_t*)p; p += WSZ;
  ushort_t* w8T_lo = (ushort_t*)p; p += WSZ;
  ushort_t* w16_hi = (ushort_t*)p; p += WSZ;
  ushort_t* w16_lo = (ushort_t*)p; p += WSZ;
  ushort_t* whx_b  = (ushort_t*)p; p += (size_t)DHID * DIN * 2;
  ushort_t* whxT   = (ushort_t*)p; p += (size_t)DIN * DHID * 2;
  ushort_t* wa_b   = (ushort_t*)p; p += (size_t)DHID * DIN * 2;   // W*Whx [2048,1024]
  ushort_t* wph_b  = (ushort_t*)p; p += (size_t)NCLS * DHID * 2;
  ushort_t* xT     = (ushort_t*)p; p += (size_t)B_SZ * SEQ_LEN * DIN * 2;   // 64 MiB
  ushort_t* z2_b   = (ushort_t*)p; p += (size_t)64 * B_SZ * DHID * 2;       // 64 MiB
  ushort_t* z4_b   = (ushort_t*)p; p += (size_t)32 * B_SZ * DHID * 2;       // 32 MiB
  ushort_t* z8_b   = (ushort_t*)p; p += (size_t)16 * B_SZ * DHID * 2;       // 16 MiB
  ushort_t* z8_lo  = (ushort_t*)p; p += (size_t)16 * B_SZ * DHID * 2;       // 16 MiB
  ushort_t* z16_b  = (ushort_t*)p; p += (size_t)8 * B_SZ * DHID * 2;        // 8 MiB
  ushort_t* z16_lo = (ushort_t*)p; p += (size_t)8 * B_SZ * DHID * 2;        // 8 MiB
  float*    Part   = (float*)p;    p += (size_t)8 * B_SZ * DHID * 4;        // 16 MiB
  ushort_t* h_hi   = (ushort_t*)p; p += (size_t)B_SZ * DHID * 2;
  ushort_t* h_lo   = (ushort_t*)p; p += (size_t)B_SZ * DHID * 2;
  float*    b2_ws  = (float*)p;    p += (size_t)DHID * 4;
  unsigned* flags  = (unsigned*)p; p += NBLK * 4;

  hipMemsetAsync(flags, 0, NBLK * 4, stream);

  // ---- fused front-end conversions ----
  k_splitT<<<dim3(32, 32), 256, 0, stream>>>(Whh, whh_hi, whh_lo, whhT_hi, whhT_lo);
  {
    int n4 = NCLS * DHID / 4;
    k_cvt<<<(n4 + 255) / 256, 256, 0, stream>>>(Wph, wph_b, n4);
  }
  k_cvtT<<<(B_SZ * SEQ_LEN * DIN / 8) / 256, 256, 0, stream>>>(x, xT);
  k_cvtW<<<dim3(DIN / 64, DHID / 64), 256, 0, stream>>>(Whx, whx_b, whxT);
  k_bvec<<<512, 256, 0, stream>>>(Whh, bh, b2_ws);

  const size_t TBLK = (size_t)512 * DHID;  // two 256-row blocks (elements)

  // ---- job descriptors ----
  BigArgs aWa = {};   // Wa = W @ Whx  [2048,1024]
  aWa.A[0] = whh_hi; aWa.B[0] = whxT;
  aWa.A[1] = whh_lo; aWa.B[1] = whxT;
  aWa.nseg = 2; aWa.klen = DHID; aWa.tA = (size_t)256 * DHID; aWa.sA = DHID;
  aWa.ldo = DIN; aWa.out_hi = wa_b; aWa.lognx = 3;           // 128 blocks

  BigArgs aW2 = {};   // W2 = W*W (3-product)
  aW2.A[0] = whh_hi; aW2.B[0] = whhT_hi;
  aW2.A[1] = whh_hi; aW2.B[1] = whhT_lo;
  aW2.A[2] = whh_lo; aW2.B[2] = whhT_hi;
  aW2.nseg = 3; aW2.klen = DHID; aW2.tA = (size_t)256 * DHID; aW2.sA = DHID;
  aW2.ldo = 2048; aW2.out_hi = w2_hi; aW2.out_lo = w2_lo; aW2.lognx = 4;  // 256

  BigArgs az2 = {};   // z2: x[2i]@Wa^T + x[2i+1]@Whx^T + b2
  az2.A[0] = xT;              az2.B[0] = wa_b;
  az2.A[1] = xT + (size_t)B_SZ * DIN; az2.B[1] = whx_b;
  az2.nseg = 2; az2.klen = DIN;
  az2.tA = (size_t)2 * B_SZ * DIN; az2.sA = DIN;
  az2.ldo = 2048; az2.bias = b2_ws; az2.out_hi = z2_b; az2.lognx = 4;     // 2048

  BigArgs aW4 = {};   // W4 = W2*W2
  aW4.A[0] = w2_hi; aW4.B[0] = w2T_hi;
  aW4.A[1] = w2_hi; aW4.B[1] = w2T_lo;
  aW4.A[2] = w2_lo; aW4.B[2] = w2T_hi;
  aW4.nseg = 3; aW4.klen = DHID; aW4.tA = (size_t)256 * DHID; aW4.sA = DHID;
  aW4.ldo = 2048; aW4.out_hi = w4_hi; aW4.out_lo = w4_lo; aW4.lognx = 4;  // 256

  BigArgs az4 = {};   // z4 = z2[2i]*W2^T + z2[2i+1]
  az4.A[0] = z2_b; az4.B[0] = w2_hi; az4.nseg = 1; az4.klen = DHID;
  az4.tA = TBLK; az4.sA = DHID;
  az4.D = z2_b + (size_t)256 * DHID; az4.tD = TBLK;
  az4.ldo = 2048; az4.out_hi = z4_b; az4.lognx = 4;                       // 1024

  BigArgs aW8 = {};   // W8 = W4*W4
  aW8.A[0] = w4_hi; aW8.B[0] = w4T_hi;
  aW8.A[1] = w4_hi; aW8.B[1] = w4T_lo;
  aW8.A[2] = w4_lo; aW8.B[2] = w4T_hi;
  aW8.nseg = 3; aW8.klen = DHID; aW8.tA = (size_t)256 * DHID; aW8.sA = DHID;
  aW8.ldo = 2048; aW8.out_hi = w8_hi; aW8.out_lo = w8_lo; aW8.lognx = 4;  // 256

  BigArgs az8 = {};   // z8 = z4[2i]*W4^T + z4[2i+1] (with lo residual)
  az8.A[0] = z4_b; az8.B[0] = w4_hi; az8.nseg = 1; az8.klen = DHID;
  az8.tA = TBLK; az8.sA = DHID;
  az8.D = z4_b + (size_t)256 * DHID; az8.tD = TBLK;
  az8.ldo = 2048; az8.out_hi = z8_b; az8.out_lo = z8_lo; az8.lognx = 4;   // 512

  BigArgs aW16 = {};  // W16 = W8*W8
  aW16.A[0] = w8_hi; aW16.B[0] = w8T_hi;
  aW16.A[1] = w8_hi; aW16.B[1] = w8T_lo;
  aW16.A[2] = w8_lo; aW16.B[2] = w8T_hi;
  aW16.nseg = 3; aW16.klen = DHID; aW16.tA = (size_t)256 * DHID; aW16.sA = DHID;
  aW16.ldo = 2048; aW16.out_hi = w16_hi; aW16.out_lo = w16_lo; aW16.lognx = 4;

  BigArgs az16 = {};  // z16 = z8[2i]*W8^T (3-prod) + z8[2i+1], hi/lo out
  az16.A[0] = z8_b;  az16.B[0] = w8_hi;
  az16.A[1] = z8_b;  az16.B[1] = w8_lo;
  az16.A[2] = z8_lo; az16.B[2] = w8_hi;
  az16.nseg = 3; az16.klen = DHID; az16.tA = TBLK; az16.sA = DHID;
  az16.D = z8_b + (size_t)256 * DHID; az16.tD = TBLK;
  az16.ldo = 2048; az16.out_hi = z16_b; az16.out_lo = z16_lo; az16.lognx = 4;

  // ---- GEMM dispatches ----
  // Dependency edges: Wa -> z2; W2 -> {trb2, z4-B}; W2 _|_ z2. So run Wa
  // alone (small), then co-schedule W2 with the big z2 dispatch (fills CUs).
  k_big1<<<dim3(128), 256, 0, stream>>>(aWa);                 // Wa (dbuf)
  k_big2s<<<dim3(2304), 256, 0, stream>>>(aW2, az2, 256);     // W2 || z2 (sbuf)
  k_trb2<<<dim3(32, 32), 256, 0, stream>>>(w2_hi, w2T_hi, w2_lo, w2T_lo);
  k_big2s<<<dim3(1280), 256, 0, stream>>>(aW4, az4, 256);     // W4 || z4 (sbuf)
  k_trb2<<<dim3(32, 32), 256, 0, stream>>>(w4_hi, w4T_hi, w4_lo, w4T_lo);
  k_big2s<<<dim3(768), 256, 0, stream>>>(aW8, az8, 256);      // W8 || z8 (sbuf)
  k_trb2<<<dim3(32, 32), 256, 0, stream>>>(w8_hi, w8T_hi, w8_lo, w8T_lo);
  k_big2<<<dim3(512), 256, 0, stream>>>(aW16, az16, 256);     // W16 || z16 (dbuf)

  // ---- persistent recurrence: 7 rounds of 16 steps ----
  k_rnn<<<dim3(NBLK), 512, 0, stream>>>(w16_hi, w16_lo, h_hi, h_lo,
                                        z16_b, z16_lo, Part, flags);

  // ---- readout: p = h_127 @ Wph^T + b_p ----
  {
    Args a = {};
    a.seg[0] = { h_hi, wph_b, DHID, DHID, DHID };
    a.seg[1] = { h_lo, wph_b, DHID, DHID, DHID };
    a.n_seg = 2; a.n_iters = 2 * DHID / 64;
    a.bias = bp; a.out_hi = nullptr; a.out_lo = nullptr;
    a.out_f32 = (float*)d_out; a.ldo = NCLS;
    k_gemm<<<dim3(NCLS / 64, B_SZ / 32), 256, 0, stream>>>(a);
  }
}

// Round 10
// 994.537 us; speedup vs baseline: 1.0232x; 1.0232x over previous
//
#include <hip/hip_runtime.h>
#include <stdint.h>

// ---------------- problem constants ----------------
#define B_SZ   256
#define SEQ_LEN 128
#define DIN    1024
#define DHID   2048
#define NCLS   1024
#define NBLK   256   // persistent grid = #CUs
#define NROUND 8     // 16-step blocking: h_15, h_31, ..., h_127

typedef unsigned short ushort_t;
typedef short bf16x8 __attribute__((ext_vector_type(8)));
typedef float f32x16 __attribute__((ext_vector_type(16)));
typedef ushort_t u16x8 __attribute__((ext_vector_type(8)));

__device__ __forceinline__ ushort_t f32_to_bf16(float f) {
  uint32_t u = __builtin_bit_cast(uint32_t, f);
  u = (u + 0x7FFFu + ((u >> 16) & 1u)) >> 16;
  return (ushort_t)u;
}
__device__ __forceinline__ float bf16_to_f32(ushort_t h) {
  uint32_t u = ((uint32_t)h) << 16;
  return __builtin_bit_cast(float, u);
}

// async global->LDS, 16B per lane (cached path)
__device__ __forceinline__ void llds16(const ushort_t* g, ushort_t* l) {
  __builtin_amdgcn_global_load_lds(
      (const __attribute__((address_space(1))) void*)g,
      (__attribute__((address_space(3))) void*)l, 16, 0, 0);
}

__device__ __forceinline__ void cstore_f32(float* p, float v) {
  __hip_atomic_store(p, v, __ATOMIC_RELAXED, __HIP_MEMORY_SCOPE_AGENT);
}
__device__ __forceinline__ void cstore_u64(void* p, uint64_t v) {
  __hip_atomic_store((uint64_t*)p, v, __ATOMIC_RELAXED, __HIP_MEMORY_SCOPE_AGENT);
}
__device__ __forceinline__ uint64_t cload_u64(const void* p) {
  return __hip_atomic_load((const uint64_t*)p, __ATOMIC_RELAXED, __HIP_MEMORY_SCOPE_AGENT);
}
__device__ __forceinline__ void cstore_u32(unsigned* p, unsigned v) {
  __hip_atomic_store(p, v, __ATOMIC_RELAXED, __HIP_MEMORY_SCOPE_AGENT);
}
__device__ __forceinline__ unsigned cload_u32(const unsigned* p) {
  return __hip_atomic_load(p, __ATOMIC_RELAXED, __HIP_MEMORY_SCOPE_AGENT);
}

// contention-free grid barrier: per-block flag STORE (no RMW serialization),
// wave0 polls all 256 flags (4 per lane), ballot-all.
__device__ __forceinline__ void gsync(unsigned* flags, unsigned ep) {
  __syncthreads();
  if (threadIdx.x == 0) cstore_u32(&flags[blockIdx.x], ep);
  if (threadIdx.x < 64) {
    const unsigned* f = flags + threadIdx.x * 4;
    for (;;) {
      unsigned a = cload_u32(f + 0), b = cload_u32(f + 1);
      unsigned c = cload_u32(f + 2), d = cload_u32(f + 3);
      bool ok = (a >= ep) & (b >= ep) & (c >= ep) & (d >= ep);
      if (__ballot(ok) == ~0ull) break;
      __builtin_amdgcn_s_sleep(1);
    }
  }
  __syncthreads();
}

// ---------------- fused conversion / transpose kernels ----------------
// Whh f32 -> {hi, lo, hiT, loT} in ONE pass.
__global__ void k_splitT(const float* __restrict__ src, ushort_t* __restrict__ hi,
                         ushort_t* __restrict__ lo, ushort_t* __restrict__ hiT,
                         ushort_t* __restrict__ loT) {
  __shared__ ushort_t th[64][65];
  __shared__ ushort_t tl[64][65];
  const int bx = blockIdx.x * 64, by = blockIdx.y * 64;
  const int c = threadIdx.x & 63, r0 = (threadIdx.x >> 6) * 16;
#pragma unroll
  for (int i = 0; i < 16; ++i) {
    size_t o = (size_t)(by + r0 + i) * DHID + bx + c;
    float v = src[o];
    ushort_t hh = f32_to_bf16(v);
    ushort_t ll = f32_to_bf16(v - bf16_to_f32(hh));
    hi[o] = hh;
    lo[o] = ll;
    th[r0 + i][c] = hh;
    tl[r0 + i][c] = ll;
  }
  __syncthreads();
#pragma unroll
  for (int i = 0; i < 16; ++i) {
    size_t o = (size_t)(bx + r0 + i) * DHID + by + c;
    hiT[o] = th[c][r0 + i];
    loT[o] = tl[c][r0 + i];
  }
}

// paired bf16 2048x2048 transpose: two matrices per launch
__global__ void k_trb2(const ushort_t* __restrict__ sA, ushort_t* __restrict__ dA,
                       const ushort_t* __restrict__ sB, ushort_t* __restrict__ dB) {
  __shared__ ushort_t ta[64][65];
  __shared__ ushort_t tb[64][65];
  const int bx = blockIdx.x * 64, by = blockIdx.y * 64;
  const int c = threadIdx.x & 63, r0 = (threadIdx.x >> 6) * 16;
#pragma unroll
  for (int i = 0; i < 16; ++i) {
    size_t o = (size_t)(by + r0 + i) * DHID + bx + c;
    ta[r0 + i][c] = sA[o];
    tb[r0 + i][c] = sB[o];
  }
  __syncthreads();
#pragma unroll
  for (int i = 0; i < 16; ++i) {
    size_t o = (size_t)(bx + r0 + i) * DHID + by + c;
    dA[o] = ta[c][r0 + i];
    dB[o] = tb[c][r0 + i];
  }
}

// Whx f32 [DHID][DIN] -> bf16 d [DHID][DIN] + dT [DIN][DHID]
__global__ void k_cvtW(const float* __restrict__ src, ushort_t* __restrict__ d,
                       ushort_t* __restrict__ dT) {
  __shared__ ushort_t t[64][65];
  const int bx = blockIdx.x * 64, by = blockIdx.y * 64;  // bx: DIN cols, by: DHID rows
  const int c = threadIdx.x & 63, r0 = (threadIdx.x >> 6) * 16;
#pragma unroll
  for (int i = 0; i < 16; ++i) {
    size_t o = (size_t)(by + r0 + i) * DIN + bx + c;
    ushort_t hh = f32_to_bf16(src[o]);
    d[o] = hh;
    t[r0 + i][c] = hh;
  }
  __syncthreads();
#pragma unroll
  for (int i = 0; i < 16; ++i)
    dT[(size_t)(bx + r0 + i) * DHID + by + c] = t[c][r0 + i];
}

__global__ void k_cvt(const float* __restrict__ s, ushort_t* __restrict__ d, int n4) {
  int i = blockIdx.x * 256 + threadIdx.x;
  if (i >= n4) return;
  float4 v = ((const float4*)s)[i];
  ushort4 hv;
  hv.x = f32_to_bf16(v.x); hv.y = f32_to_bf16(v.y);
  hv.z = f32_to_bf16(v.z); hv.w = f32_to_bf16(v.w);
  ((ushort4*)d)[i] = hv;
}

// fused f32->bf16 convert + [B][S][D] -> [S][B][D] time-major transpose.
__global__ void k_cvtT(const float* __restrict__ s, ushort_t* __restrict__ d) {
  int i = blockIdx.x * 256 + threadIdx.x;      // over B*S*D/8
  int dd = (i & (DIN / 8 - 1)) * 8;
  int bs = i >> 7;                             // b*SEQ_LEN + t
  int b = bs >> 7;                             // /SEQ_LEN
  int t = bs & (SEQ_LEN - 1);
  const float* src = s + (size_t)bs * DIN + dd;
  float4 v0 = *(const float4*)src;
  float4 v1 = *(const float4*)(src + 4);
  u16x8 hv;
  hv[0] = f32_to_bf16(v0.x); hv[1] = f32_to_bf16(v0.y);
  hv[2] = f32_to_bf16(v0.z); hv[3] = f32_to_bf16(v0.w);
  hv[4] = f32_to_bf16(v1.x); hv[5] = f32_to_bf16(v1.y);
  hv[6] = f32_to_bf16(v1.z); hv[7] = f32_to_bf16(v1.w);
  *(u16x8*)(d + ((size_t)t * B_SZ + b) * DIN + dd) = hv;
}

// b2[h] = b[h] + sum_j W[h,j] b[j]  (f32, one wave per row)
__global__ void k_bvec(const float* __restrict__ W, const float* __restrict__ b,
                       float* __restrict__ out) {
  int row = (blockIdx.x * blockDim.x + threadIdx.x) >> 6;
  int lane = threadIdx.x & 63;
  if (row >= DHID) return;
  float s = 0.0f;
  for (int j = lane; j < DHID; j += 64) s += W[(size_t)row * DHID + j] * b[j];
#pragma unroll
  for (int off = 32; off; off >>= 1) s += __shfl_down(s, off);
  if (lane == 0) out[row] = b[row] + s;
}

// ---------------- generic 128x128-tile GEMM, two cores ----------
// C[M,N] = sum_seg A_seg * B_seg^T (+bias[col] | +bf16 D), out bf16,
// optional hi/lo split. A row r -> element offset (r>>8)*tA + (r&255)*sA.
// B is [N, klen] row-major. Flat grid, NATURAL launch order (no XCD swizzle).
//
// Session ledger (locked R7 champion config, 994.9 us):
//  R3: runtime-ref select over byval args -> kernarg scratch spill. AVOID.
//  R6: transposed-output epilogue fusion -> regalloc collapse + scratch. AVOID.
//  R8: 256^2 4-phase counted-vmcnt core -> NEUTRAL (same ~29% MfmaUtil);
//      the ~660-740 TF ceiling is not schedule-bound at these shapes.
//  R9: peeling Wa into its own 128-blk dispatch (to merge W2||z2) -> NET LOSS:
//      merged sbuf co-run hit 741 TF aggregate, but the half-idle Wa dispatch
//      ahead of the serial chain erased the gain. Keep [W2||Wa] -> [z2].
struct BigArgs {
  const ushort_t* A[3];
  const ushort_t* B[3];
  int nseg;
  int klen;
  size_t tA, sA;
  size_t ldo;          // output row stride (elements)
  const ushort_t* D;   // bf16 D or null; row map (r>>8)*tD + (r&255)*2048
  size_t tD;
  const float* bias;   // or null
  ushort_t* out_hi;
  ushort_t* out_lo;    // or null
  int lognx;           // log2(N/128)
};

// epilogue shared by both cores (validated R1-R5 codegen)
__device__ __forceinline__ void big_epi(const BigArgs& a, f32x16 (&acc)[2][2],
                                        int bm0, int bn0) {
  const int tid = threadIdx.x, lane = tid & 63, wv = tid >> 6;
  const int l31 = lane & 31, half = lane >> 5;
  int gm0 = bm0 + (wv & 1) * 64, gn0 = bn0 + (wv >> 1) * 64;
#pragma unroll
  for (int mi = 0; mi < 2; ++mi)
#pragma unroll
    for (int ni = 0; ni < 2; ++ni)
#pragma unroll
      for (int r = 0; r < 16; ++r) {
        int row = gm0 + mi * 32 + (r & 3) + 8 * (r >> 2) + 4 * half;
        int col = gn0 + ni * 32 + l31;
        float v = acc[mi][ni][r];
        if (a.bias) v += a.bias[col];
        if (a.D)
          v += bf16_to_f32(a.D[(size_t)(row >> 8) * a.tD +
                               (size_t)(row & 255) * 2048 + col]);
        ushort_t hh = f32_to_bf16(v);
        a.out_hi[(size_t)row * a.ldo + col] = hh;
        if (a.out_lo)
          a.out_lo[(size_t)row * a.ldo + col] = f32_to_bf16(v - bf16_to_f32(hh));
      }
}

// ---- dbuf core (validated R1/R4) ----
__device__ __forceinline__ void big_body_db(const BigArgs& a, int wg) {
  __shared__ __align__(16) ushort_t lds[32768];  // 64KB
  const int tid = threadIdx.x, lane = tid & 63, wv = tid >> 6;
  const int l31 = lane & 31, half = lane >> 5;

  const int bn0 = (wg & ((1 << a.lognx) - 1)) * 128;
  const int bm0 = (wg >> a.lognx) * 128;
  const int t_ = bm0 >> 8, mrem = bm0 & 255;
  const int kit = a.klen >> 6;

  f32x16 acc[2][2];
#pragma unroll
  for (int p = 0; p < 2; ++p)
#pragma unroll
    for (int q = 0; q < 2; ++q)
#pragma unroll
      for (int r = 0; r < 16; ++r) acc[p][q][r] = 0.0f;

  auto stage = [&](int buf, int i) {
    int seg = 0, ii = i;
    while (ii >= kit) { ii -= kit; ++seg; }
    const int kc = ii * 64;
    const ushort_t* Ab = a.A[seg];
    const ushort_t* Bb = a.B[seg];
#pragma unroll
    for (int j = 0; j < 4; ++j) {
      int s = tid + 256 * j;
      int prow = s >> 3, glc = (s & 7) ^ (prow & 7);
      llds16(Ab + (size_t)t_ * a.tA + (size_t)(mrem + prow) * a.sA + (kc + glc * 8),
             &lds[(size_t)(buf * 16384 + (wv * 64 + 256 * j) * 16) / 2]);
      llds16(Bb + (size_t)(bn0 + prow) * a.klen + (kc + glc * 8),
             &lds[(size_t)(32768 + buf * 16384 + (wv * 64 + 256 * j) * 16) / 2]);
    }
  };

  const int nit = a.nseg * kit;
  stage(0, 0);
  for (int i = 0; i < nit; ++i) {
    int buf = i & 1;
    if (i + 1 < nit) {
      stage(buf ^ 1, i + 1);
      __builtin_amdgcn_s_waitcnt(0x3FF0 | 8);
    } else {
      __builtin_amdgcn_s_waitcnt(0x3FF0);
    }
    __builtin_amdgcn_s_barrier();
    const ushort_t* At = &lds[buf * 8192];
    const ushort_t* Bt = &lds[16384 + buf * 8192];
#pragma unroll
    for (int ks = 0; ks < 4; ++ks) {
      int ch = ks * 2 + half;
      bf16x8 af[2], bf_[2];
#pragma unroll
      for (int mi = 0; mi < 2; ++mi) {
        int row = (wv & 1) * 64 + mi * 32 + l31;
        int pch = ch ^ (row & 7);
        af[mi] = *(const bf16x8*)&At[row * 64 + pch * 8];
      }
#pragma unroll
      for (int ni = 0; ni < 2; ++ni) {
        int row = (wv >> 1) * 64 + ni * 32 + l31;
        int pch = ch ^ (row & 7);
        bf_[ni] = *(const bf16x8*)&Bt[row * 64 + pch * 8];
      }
#pragma unroll
      for (int mi = 0; mi < 2; ++mi)
#pragma unroll
        for (int ni = 0; ni < 2; ++ni)
          acc[mi][ni] = __builtin_amdgcn_mfma_f32_32x32x16_bf16(
              af[mi], bf_[ni], acc[mi][ni], 0, 0, 0);
    }
    __builtin_amdgcn_s_barrier();
  }
  big_epi(a, acc, bm0, bn0);
}

// ---- m97 single-buffer core (validated R2) ----
__device__ __forceinline__ void big_body_sb(const BigArgs& a, int wg) {
  __shared__ __align__(16) ushort_t lds[16384];  // 32KB
  const int tid = threadIdx.x, lane = tid & 63, wv = tid >> 6;
  const int l31 = lane & 31, half = lane >> 5;

  const int bn0 = (wg & ((1 << a.lognx) - 1)) * 128;
  const int bm0 = (wg >> a.lognx) * 128;
  const int t_ = bm0 >> 8, mrem = bm0 & 255;
  const int kit = a.klen >> 6;

  f32x16 acc[2][2];
#pragma unroll
  for (int p = 0; p < 2; ++p)
#pragma unroll
    for (int q = 0; q < 2; ++q)
#pragma unroll
      for (int r = 0; r < 16; ++r) acc[p][q][r] = 0.0f;

  auto stage = [&](int i) {
    int seg = 0, ii = i;
    while (ii >= kit) { ii -= kit; ++seg; }
    const int kc = ii * 64;
    const ushort_t* Ab = a.A[seg];
    const ushort_t* Bb = a.B[seg];
#pragma unroll
    for (int j = 0; j < 4; ++j) {
      int s = tid + 256 * j;
      int prow = s >> 3, glc = (s & 7) ^ (prow & 7);
      llds16(Ab + (size_t)t_ * a.tA + (size_t)(mrem + prow) * a.sA + (kc + glc * 8),
             &lds[(size_t)((wv * 64 + 256 * j) * 16) / 2]);
      llds16(Bb + (size_t)(bn0 + prow) * a.klen + (kc + glc * 8),
             &lds[(size_t)(16384 + (wv * 64 + 256 * j) * 16) / 2]);
    }
  };

  const int nit = a.nseg * kit;
  for (int i = 0; i < nit; ++i) {
    stage(i);
    __builtin_amdgcn_s_waitcnt(0x3FF0);
    __builtin_amdgcn_s_barrier();
    const ushort_t* At = &lds[0];
    const ushort_t* Bt = &lds[8192];
#pragma unroll
    for (int ks = 0; ks < 4; ++ks) {
      int ch = ks * 2 + half;
      bf16x8 af[2], bf_[2];
#pragma unroll
      for (int mi = 0; mi < 2; ++mi) {
        int row = (wv & 1) * 64 + mi * 32 + l31;
        int pch = ch ^ (row & 7);
        af[mi] = *(const bf16x8*)&At[row * 64 + pch * 8];
      }
#pragma unroll
      for (int ni = 0; ni < 2; ++ni) {
        int row = (wv >> 1) * 64 + ni * 32 + l31;
        int pch = ch ^ (row & 7);
        bf_[ni] = *(const bf16x8*)&Bt[row * 64 + pch * 8];
      }
#pragma unroll
      for (int mi = 0; mi < 2; ++mi)
#pragma unroll
        for (int ni = 0; ni < 2; ++ni)
          acc[mi][ni] = __builtin_amdgcn_mfma_f32_32x32x16_bf16(
              af[mi], bf_[ni], acc[mi][ni], 0, 0, 0);
    }
    __builtin_amdgcn_s_barrier();
  }
  big_epi(a, acc, bm0, bn0);
}

// dbuf wrappers (<=2 blocks/CU dispatches)
__global__ __launch_bounds__(256, 1) void k_big2(BigArgs a0, BigArgs a1, int nblk0) {
  int wg = blockIdx.x;
  if (wg < nblk0) {
    big_body_db(a0, wg);
  } else {
    big_body_db(a1, wg - nblk0);
  }
}

// single-buffer wrappers (>=3 blocks/CU dispatches)
__global__ __launch_bounds__(256, 4) void k_big1s(BigArgs a) {
  big_body_sb(a, blockIdx.x);
}
__global__ __launch_bounds__(256, 4) void k_big2s(BigArgs a0, BigArgs a1, int nblk0) {
  int wg = blockIdx.x;
  if (wg < nblk0) {
    big_body_sb(a0, wg);
  } else {
    big_body_sb(a1, wg - nblk0);
  }
}

// ---------------- persistent recurrence kernel (512 threads, 8 waves) -------
__global__ __launch_bounds__(512, 2) void k_rnn(
    const ushort_t* __restrict__ w_hi, const ushort_t* __restrict__ w_lo,
    ushort_t* __restrict__ h_hi, ushort_t* __restrict__ h_lo,
    const ushort_t* __restrict__ z_hi, const ushort_t* __restrict__ z_lo,
    float* __restrict__ P, unsigned* __restrict__ flags) {
  __shared__ __align__(16) ushort_t lds[81920];  // 160 KiB
  char* ldsb = (char*)&lds[0];

  const int tid = threadIdx.x, lane = tid & 63, wv = tid >> 6;
  const int l31 = lane & 31, half = lane >> 5;
  const int kslice = wv & 1, mq = (wv >> 1) & 1, nq = wv >> 2;
  const int b = blockIdx.x;
  const int kb = b & 7, nb = (b >> 3) & 15, mb = b >> 7;
  const int n0 = nb * 128, k0 = kb * 256, m0 = mb * 128;

  // ---- pin W16 slices in LDS (once; cached path) ----
#pragma unroll
  for (int hl = 0; hl < 2; ++hl) {
    const ushort_t* W = hl ? w_lo : w_hi;
    for (int p = 0; p < 4; ++p)
#pragma unroll
      for (int j = 0; j < 2; ++j) {
        int s = tid + 512 * j;
        int prow = s >> 3, glc = (s & 7) ^ (prow & 7);
        const ushort_t* g = W + (size_t)(n0 + prow) * DHID + (k0 + p * 64 + glc * 8);
        ushort_t* d = (ushort_t*)(ldsb + hl * 65536 + p * 16384 + (wv * 64 + 512 * j) * 16);
        llds16(g, d);
      }
  }
  __builtin_amdgcn_s_waitcnt(0x3FF0);
  __syncthreads();

  const int srow0 = wv * 16 + (lane >> 4);
  const int skk   = 4 * (lane & 15);
  const int sg    = (lane & 15) >> 1;
  const int ssub  = lane & 1;

  uint64_t R[4][4];

  auto regload = [&](int slot, int c) {
    const ushort_t* src = (c < 4) ? h_hi : h_lo;
    const int p = c & 3;
#pragma unroll
    for (int i = 0; i < 4; ++i)
      R[slot][i] = cload_u64(src + (size_t)(m0 + srow0 + 4 * i) * DHID +
                             (k0 + p * 64 + skk));
  };
  auto dswrite = [&](int buf, int slot) {
#pragma unroll
    for (int i = 0; i < 4; ++i) {
      int lr = srow0 + 4 * i;
      *(uint64_t*)(ldsb + 131072 + buf * 16384 + lr * 128 +
                   ((sg ^ (lr & 7)) * 16) + ssub * 8) = R[slot][i];
    }
  };

  auto phaseB = [&](ushort4 zq, ushort4 zl, bool withP) {
    const int r = b;
    const int c0 = tid * 4;
    float v[4] = {bf16_to_f32(zq.x) + bf16_to_f32(zl.x),
                  bf16_to_f32(zq.y) + bf16_to_f32(zl.y),
                  bf16_to_f32(zq.z) + bf16_to_f32(zl.z),
                  bf16_to_f32(zq.w) + bf16_to_f32(zl.w)};
    if (withP) {
#pragma unroll
      for (int k = 0; k < 8; ++k) {
        const float* pp = P + ((size_t)k * B_SZ + r) * DHID + c0;
#pragma unroll
        for (int j = 0; j < 2; ++j) {
          uint64_t q = cload_u64((const uint64_t*)pp + j);
          float2 f = __builtin_bit_cast(float2, q);
          v[2 * j]     += f.x;
          v[2 * j + 1] += f.y;
        }
      }
    }
    ushort_t hh[4], ll[4];
#pragma unroll
    for (int e = 0; e < 4; ++e) {
      hh[e] = f32_to_bf16(v[e]);
      ll[e] = f32_to_bf16(v[e] - bf16_to_f32(hh[e]));
    }
    uint64_t q0, q1;
    __builtin_memcpy(&q0, &hh[0], 8);
    __builtin_memcpy(&q1, &ll[0], 8);
    cstore_u64(h_hi + (size_t)r * DHID + c0, q0);
    cstore_u64(h_lo + (size_t)r * DHID + c0, q1);
  };

  unsigned ep = 1;
  {
    ushort4 zq = *(const ushort4*)(z_hi + (size_t)b * DHID + tid * 4);
    ushort4 zl = *(const ushort4*)(z_lo + (size_t)b * DHID + tid * 4);
    phaseB(zq, zl, false);  // h_15 = z16[0]
  }
  gsync(flags, ep); ++ep;

  for (int j = 1; j < NROUND; ++j) {
    f32x16 acc[2][2];
#pragma unroll
    for (int p = 0; p < 2; ++p)
#pragma unroll
      for (int q = 0; q < 2; ++q)
#pragma unroll
        for (int r = 0; r < 16; ++r) acc[p][q][r] = 0.0f;

    regload(0, 0); regload(1, 1); regload(2, 2); regload(3, 3);
    dswrite(0, 0);
    __syncthreads();

    for (int c = 0; c < 8; ++c) {
      if (c + 4 <= 7) regload(c & 3, c + 4);
      if (c + 1 <= 7) dswrite((c + 1) & 1, (c + 1) & 3);

      const char* At = ldsb + 131072 + (c & 1) * 16384;
      const char* Bh = ldsb + (size_t)(c & 3) * 16384;
      const char* Bl = ldsb + 65536 + (size_t)(c & 3) * 16384;
      const bool isHi = c < 4;
#pragma unroll
      for (int ks = 0; ks < 2; ++ks) {
        const int g = (kslice * 2 + ks) * 2 + half;
        bf16x8 af[2], bh_[2], bl_[2];
#pragma unroll
        for (int mi = 0; mi < 2; ++mi) {
          int row = mq * 64 + mi * 32 + l31;
          af[mi] = *(const bf16x8*)(At + row * 128 + (g ^ (row & 7)) * 16);
        }
#pragma unroll
        for (int ni = 0; ni < 2; ++ni) {
          int row = nq * 64 + ni * 32 + l31;
          int off = row * 128 + (g ^ (row & 7)) * 16;
          bh_[ni] = *(const bf16x8*)(Bh + off);
          if (isHi) bl_[ni] = *(const bf16x8*)(Bl + off);
        }
#pragma unroll
        for (int mi = 0; mi < 2; ++mi)
#pragma unroll
          for (int ni = 0; ni < 2; ++ni) {
            acc[mi][ni] = __builtin_amdgcn_mfma_f32_32x32x16_bf16(
                af[mi], bh_[ni], acc[mi][ni], 0, 0, 0);
            if (isHi)
              acc[mi][ni] = __builtin_amdgcn_mfma_f32_32x32x16_bf16(
                  af[mi], bl_[ni], acc[mi][ni], 0, 0, 0);
          }
      }
      __syncthreads();
    }

    // ---- reduce kslice pairs through LDS ----
    {
      float* scr = (float*)(ldsb + 131072);
      const int pr = mq * 2 + nq;
#pragma unroll
      for (int r = 0; r < 2; ++r) {
        if (kslice == 1) {
#pragma unroll
          for (int ni = 0; ni < 2; ++ni)
#pragma unroll
            for (int reg = 0; reg < 16; ++reg) {
              int row32 = (reg & 3) + 8 * (reg >> 2) + 4 * half;
              scr[pr * 2048 + row32 * 64 + ni * 32 + l31] = acc[r][ni][reg];
            }
        }
        __syncthreads();
        if (kslice == 0) {
#pragma unroll
          for (int ni = 0; ni < 2; ++ni)
#pragma unroll
            for (int reg = 0; reg < 16; ++reg) {
              int row32 = (reg & 3) + 8 * (reg >> 2) + 4 * half;
              acc[r][ni][reg] += scr[pr * 2048 + row32 * 64 + ni * 32 + l31];
            }
        }
        __syncthreads();
      }
    }

    if (kslice == 0) {
      float* Pt = P + (size_t)kb * (B_SZ * DHID);
#pragma unroll
      for (int mi = 0; mi < 2; ++mi)
#pragma unroll
        for (int ni = 0; ni < 2; ++ni)
#pragma unroll
          for (int reg = 0; reg < 16; ++reg) {
            int row = m0 + mq * 64 + mi * 32 + (reg & 3) + 8 * (reg >> 2) + 4 * half;
            int col = n0 + nq * 64 + ni * 32 + l31;
            cstore_f32(&Pt[(size_t)row * DHID + col], acc[mi][ni][reg]);
          }
    }
    ushort4 zq = *(const ushort4*)(z_hi + ((size_t)j * 256 + b) * DHID + tid * 4);
    ushort4 zl = *(const ushort4*)(z_lo + ((size_t)j * 256 + b) * DHID + tid * 4);
    gsync(flags, ep); ++ep;

    phaseB(zq, zl, true);
    gsync(flags, ep); ++ep;
  }
}

// ---------------- readout GEMM (validated R2 segmented kernel) -----------
struct Seg {
  const ushort_t* A;
  const ushort_t* B;
  int a_stride;
  int b_stride;
  int k_len;
};
struct Args {
  Seg seg[4];
  int n_seg;
  int n_iters;
  const float* bias;
  ushort_t* out_hi;
  ushort_t* out_lo;
  float* out_f32;
  int ldo;
};

#define DEPTH 6
__global__ __launch_bounds__(256, 1) void k_gemm(Args args) {
  __shared__ __align__(16) char pool[DEPTH * 12288];
  const int tid = threadIdx.x, lane = tid & 63, wv = tid >> 6;
  const int bm0 = blockIdx.y * 32, bn0 = blockIdx.x * 64;

  f32x16 acc[2];
#pragma unroll
  for (int c = 0; c < 2; ++c)
#pragma unroll
    for (int r = 0; r < 16; ++r) acc[c][r] = 0.0f;

  const int prow0 = tid >> 3;
  const int glc0 = (tid & 7) ^ (prow0 & 7);
  const int prow1 = (tid + 256) >> 3;
  const int glc1 = (tid & 7) ^ (prow1 & 7);

  auto stage = [&](int buf, const Seg& sg, int k0) {
    const ushort_t* ga = sg.A + (size_t)(bm0 + prow0) * sg.a_stride + (k0 + glc0 * 8);
    const ushort_t* gb0 = sg.B + (size_t)(bn0 + prow0) * sg.b_stride + (k0 + glc0 * 8);
    const ushort_t* gb1 = sg.B + (size_t)(bn0 + prow1) * sg.b_stride + (k0 + glc1 * 8);
    ushort_t* la = (ushort_t*)(pool + buf * 12288) + wv * 512;
    ushort_t* lb = (ushort_t*)(pool + buf * 12288 + 4096) + wv * 512;
    llds16(ga, la);
    llds16(gb0, lb);
    llds16(gb1, lb + 2048);
  };

  const int nit = args.n_iters;
  int sc = 0, kc = 0;
  int nst = nit < (DEPTH - 1) ? nit : (DEPTH - 1);
  for (int s = 0; s < nst; ++s) {
    stage(s, args.seg[sc], kc);
    kc += 64;
    if (kc >= args.seg[sc].k_len) { kc = 0; ++sc; }
  }

  const int half = lane >> 5, l31 = lane & 31;
  const int lch = wv * 2 + half;
  int sb = DEPTH - 1, cb = 0;

  for (int i = 0; i < nit; ++i) {
    int ahead = nit - 1 - i;
    if (ahead > DEPTH - 1) ahead = DEPTH - 1;
    if (i + DEPTH - 1 < nit) {
      stage(sb, args.seg[sc], kc);
      if (++sb == DEPTH) sb = 0;
      kc += 64;
      if (kc >= args.seg[sc].k_len) { kc = 0; ++sc; }
    }
    switch (ahead) {
      case 5: __builtin_amdgcn_s_waitcnt(0x3FF0 | 15); break;
      case 4: __builtin_amdgcn_s_waitcnt(0x3FF0 | 12); break;
      case 3: __builtin_amdgcn_s_waitcnt(0x3FF0 | 9); break;
      case 2: __builtin_amdgcn_s_waitcnt(0x3FF0 | 6); break;
      case 1: __builtin_amdgcn_s_waitcnt(0x3FF0 | 3); break;
      default: __builtin_amdgcn_s_waitcnt(0x3FF0 | 0); break;
    }
    __builtin_amdgcn_s_barrier();

    const ushort_t* tA = (const ushort_t*)(pool + cb * 12288);
    const ushort_t* tB = tA + 2048;
    bf16x8 af, bfm[2];
    {
      int row = l31;
      int pch = lch ^ (row & 7);
      af = *(const bf16x8*)&tA[row * 64 + pch * 8];
    }
#pragma unroll
    for (int ni = 0; ni < 2; ++ni) {
      int row = ni * 32 + l31;
      int pch = lch ^ (row & 7);
      bfm[ni] = *(const bf16x8*)&tB[row * 64 + pch * 8];
    }
#pragma unroll
    for (int ni = 0; ni < 2; ++ni)
      acc[ni] = __builtin_amdgcn_mfma_f32_32x32x16_bf16(af, bfm[ni], acc[ni], 0, 0, 0);

    if (++cb == DEPTH) cb = 0;
    __builtin_amdgcn_s_barrier();
  }

  __syncthreads();
  float* red = (float*)pool + wv * 2048;
#pragma unroll
  for (int ni = 0; ni < 2; ++ni)
#pragma unroll
    for (int r = 0; r < 16; ++r) {
      int row = (r & 3) + 8 * (r >> 2) + 4 * half;
      int col = ni * 32 + l31;
      red[row * 64 + col] = acc[ni][r];
    }
  __syncthreads();

  const float* r0 = (const float*)pool;
  const float* r1 = r0 + 2048;
  const float* r2 = r0 + 4096;
  const float* r3 = r0 + 6144;
#pragma unroll
  for (int j = 0; j < 8; ++j) {
    int e = j * 256 + tid;
    int row = e >> 6, col = e & 63;
    float v = r0[e] + r1[e] + r2[e] + r3[e] + args.bias[bn0 + col];
    size_t o = (size_t)(bm0 + row) * args.ldo + (bn0 + col);
    if (args.out_f32) {
      args.out_f32[o] = v;
    } else {
      ushort_t h = f32_to_bf16(v);
      args.out_hi[o] = h;
      args.out_lo[o] = f32_to_bf16(v - bf16_to_f32(h));
    }
  }
}

// ---------------- launch ----------------
extern "C" void kernel_launch(void* const* d_in, const int* in_sizes, int n_in,
                              void* d_out, int out_size, void* d_ws, size_t ws_size,
                              hipStream_t stream) {
  const float* x   = (const float*)d_in[0];
  const float* Whx = (const float*)d_in[1];
  const float* Whh = (const float*)d_in[2];
  const float* Wph = (const float*)d_in[3];
  const float* bh  = (const float*)d_in[4];
  const float* bp  = (const float*)d_in[5];

  const size_t WSZ = (size_t)DHID * DHID * 2;  // 8 MiB (one bf16 2048^2)
  char* p = (char*)d_ws;
  ushort_t* whh_hi = (ushort_t*)p; p += WSZ;
  ushort_t* whh_lo = (ushort_t*)p; p += WSZ;
  ushort_t* whhT_hi= (ushort_t*)p; p += WSZ;
  ushort_t* whhT_lo= (ushort_t*)p; p += WSZ;
  ushort_t* w2_hi  = (ushort_t*)p; p += WSZ;
  ushort_t* w2_lo  = (ushort_t*)p; p += WSZ;
  ushort_t* w2T_hi = (ushort_t*)p; p += WSZ;
  ushort_t* w2T_lo = (ushort_t*)p; p += WSZ;
  ushort_t* w4_hi  = (ushort_t*)p; p += WSZ;
  ushort_t* w4_lo  = (ushort_t*)p; p += WSZ;
  ushort_t* w4T_hi = (ushort_t*)p; p += WSZ;
  ushort_t* w4T_lo = (ushort_t*)p; p += WSZ;
  ushort_t* w8_hi  = (ushort_t*)p; p += WSZ;
  ushort_t* w8_lo  = (ushort_t*)p; p += WSZ;
  ushort_t* w8T_hi = (ushort_t*)p; p += WSZ;
  ushort_t* w8T_lo = (ushort_t*)p; p += WSZ;
  ushort_t* w16_hi = (ushort_t*)p; p += WSZ;
  ushort_t* w16_lo = (ushort_t*)p; p += WSZ;
  ushort_t* whx_b  = (ushort_t*)p; p += (size_t)DHID * DIN * 2;
  ushort_t* whxT   = (ushort_t*)p; p += (size_t)DIN * DHID * 2;
  ushort_t* wa_b   = (ushort_t*)p; p += (size_t)DHID * DIN * 2;   // W*Whx [2048,1024]
  ushort_t* wph_b  = (ushort_t*)p; p += (size_t)NCLS * DHID * 2;
  ushort_t* xT     = (ushort_t*)p; p += (size_t)B_SZ * SEQ_LEN * DIN * 2;   // 64 MiB
  ushort_t* z2_b   = (ushort_t*)p; p += (size_t)64 * B_SZ * DHID * 2;       // 64 MiB
  ushort_t* z4_b   = (ushort_t*)p; p += (size_t)32 * B_SZ * DHID * 2;       // 32 MiB
  ushort_t* z8_b   = (ushort_t*)p; p += (size_t)16 * B_SZ * DHID * 2;       // 16 MiB
  ushort_t* z8_lo  = (ushort_t*)p; p += (size_t)16 * B_SZ * DHID * 2;       // 16 MiB
  ushort_t* z16_b  = (ushort_t*)p; p += (size_t)8 * B_SZ * DHID * 2;        // 8 MiB
  ushort_t* z16_lo = (ushort_t*)p; p += (size_t)8 * B_SZ * DHID * 2;        // 8 MiB
  float*    Part   = (float*)p;    p += (size_t)8 * B_SZ * DHID * 4;        // 16 MiB
  ushort_t* h_hi   = (ushort_t*)p; p += (size_t)B_SZ * DHID * 2;
  ushort_t* h_lo   = (ushort_t*)p; p += (size_t)B_SZ * DHID * 2;
  float*    b2_ws  = (float*)p;    p += (size_t)DHID * 4;
  unsigned* flags  = (unsigned*)p; p += NBLK * 4;

  hipMemsetAsync(flags, 0, NBLK * 4, stream);

  // ---- fused front-end conversions ----
  k_splitT<<<dim3(32, 32), 256, 0, stream>>>(Whh, whh_hi, whh_lo, whhT_hi, whhT_lo);
  {
    int n4 = NCLS * DHID / 4;
    k_cvt<<<(n4 + 255) / 256, 256, 0, stream>>>(Wph, wph_b, n4);
  }
  k_cvtT<<<(B_SZ * SEQ_LEN * DIN / 8) / 256, 256, 0, stream>>>(x, xT);
  k_cvtW<<<dim3(DIN / 64, DHID / 64), 256, 0, stream>>>(Whx, whx_b, whxT);
  k_bvec<<<512, 256, 0, stream>>>(Whh, bh, b2_ws);

  const size_t TBLK = (size_t)512 * DHID;  // two 256-row blocks (elements)

  // ---- job descriptors ----
  BigArgs aWa = {};   // Wa = W @ Whx  [2048,1024]
  aWa.A[0] = whh_hi; aWa.B[0] = whxT;
  aWa.A[1] = whh_lo; aWa.B[1] = whxT;
  aWa.nseg = 2; aWa.klen = DHID; aWa.tA = (size_t)256 * DHID; aWa.sA = DHID;
  aWa.ldo = DIN; aWa.out_hi = wa_b; aWa.lognx = 3;           // 128 blocks

  BigArgs aW2 = {};   // W2 = W*W (3-product)
  aW2.A[0] = whh_hi; aW2.B[0] = whhT_hi;
  aW2.A[1] = whh_hi; aW2.B[1] = whhT_lo;
  aW2.A[2] = whh_lo; aW2.B[2] = whhT_hi;
  aW2.nseg = 3; aW2.klen = DHID; aW2.tA = (size_t)256 * DHID; aW2.sA = DHID;
  aW2.ldo = 2048; aW2.out_hi = w2_hi; aW2.out_lo = w2_lo; aW2.lognx = 4;  // 256

  BigArgs az2 = {};   // z2: x[2i]@Wa^T + x[2i+1]@Whx^T + b2
  az2.A[0] = xT;              az2.B[0] = wa_b;
  az2.A[1] = xT + (size_t)B_SZ * DIN; az2.B[1] = whx_b;
  az2.nseg = 2; az2.klen = DIN;
  az2.tA = (size_t)2 * B_SZ * DIN; az2.sA = DIN;
  az2.ldo = 2048; az2.bias = b2_ws; az2.out_hi = z2_b; az2.lognx = 4;     // 2048

  BigArgs aW4 = {};   // W4 = W2*W2
  aW4.A[0] = w2_hi; aW4.B[0] = w2T_hi;
  aW4.A[1] = w2_hi; aW4.B[1] = w2T_lo;
  aW4.A[2] = w2_lo; aW4.B[2] = w2T_hi;
  aW4.nseg = 3; aW4.klen = DHID; aW4.tA = (size_t)256 * DHID; aW4.sA = DHID;
  aW4.ldo = 2048; aW4.out_hi = w4_hi; aW4.out_lo = w4_lo; aW4.lognx = 4;  // 256

  BigArgs az4 = {};   // z4 = z2[2i]*W2^T + z2[2i+1]
  az4.A[0] = z2_b; az4.B[0] = w2_hi; az4.nseg = 1; az4.klen = DHID;
  az4.tA = TBLK; az4.sA = DHID;
  az4.D = z2_b + (size_t)256 * DHID; az4.tD = TBLK;
  az4.ldo = 2048; az4.out_hi = z4_b; az4.lognx = 4;                       // 1024

  BigArgs aW8 = {};   // W8 = W4*W4
  aW8.A[0] = w4_hi; aW8.B[0] = w4T_hi;
  aW8.A[1] = w4_hi; aW8.B[1] = w4T_lo;
  aW8.A[2] = w4_lo; aW8.B[2] = w4T_hi;
  aW8.nseg = 3; aW8.klen = DHID; aW8.tA = (size_t)256 * DHID; aW8.sA = DHID;
  aW8.ldo = 2048; aW8.out_hi = w8_hi; aW8.out_lo = w8_lo; aW8.lognx = 4;  // 256

  BigArgs az8 = {};   // z8 = z4[2i]*W4^T + z4[2i+1] (with lo residual)
  az8.A[0] = z4_b; az8.B[0] = w4_hi; az8.nseg = 1; az8.klen = DHID;
  az8.tA = TBLK; az8.sA = DHID;
  az8.D = z4_b + (size_t)256 * DHID; az8.tD = TBLK;
  az8.ldo = 2048; az8.out_hi = z8_b; az8.out_lo = z8_lo; az8.lognx = 4;   // 512

  BigArgs aW16 = {};  // W16 = W8*W8
  aW16.A[0] = w8_hi; aW16.B[0] = w8T_hi;
  aW16.A[1] = w8_hi; aW16.B[1] = w8T_lo;
  aW16.A[2] = w8_lo; aW16.B[2] = w8T_hi;
  aW16.nseg = 3; aW16.klen = DHID; aW16.tA = (size_t)256 * DHID; aW16.sA = DHID;
  aW16.ldo = 2048; aW16.out_hi = w16_hi; aW16.out_lo = w16_lo; aW16.lognx = 4;

  BigArgs az16 = {};  // z16 = z8[2i]*W8^T (3-prod) + z8[2i+1], hi/lo out
  az16.A[0] = z8_b;  az16.B[0] = w8_hi;
  az16.A[1] = z8_b;  az16.B[1] = w8_lo;
  az16.A[2] = z8_lo; az16.B[2] = w8_hi;
  az16.nseg = 3; az16.klen = DHID; az16.tA = TBLK; az16.sA = DHID;
  az16.D = z8_b + (size_t)256 * DHID; az16.tD = TBLK;
  az16.ldo = 2048; az16.out_hi = z16_b; az16.out_lo = z16_lo; az16.lognx = 4;

  // ---- GEMM dispatches: R7 champion grouping (994.9 us) ----
  k_big2<<<dim3(384), 256, 0, stream>>>(aW2, aWa, 256);       // W2 || Wa (dbuf)
  k_big1s<<<dim3(2048), 256, 0, stream>>>(az2);               // z2 (sbuf)
  k_trb2<<<dim3(32, 32), 256, 0, stream>>>(w2_hi, w2T_hi, w2_lo, w2T_lo);
  k_big2s<<<dim3(1280), 256, 0, stream>>>(aW4, az4, 256);     // W4 || z4 (sbuf)
  k_trb2<<<dim3(32, 32), 256, 0, stream>>>(w4_hi, w4T_hi, w4_lo, w4T_lo);
  k_big2s<<<dim3(768), 256, 0, stream>>>(aW8, az8, 256);      // W8 || z8 (sbuf)
  k_trb2<<<dim3(32, 32), 256, 0, stream>>>(w8_hi, w8T_hi, w8_lo, w8T_lo);
  k_big2<<<dim3(512), 256, 0, stream>>>(aW16, az16, 256);     // W16 || z16 (dbuf)

  // ---- persistent recurrence: 7 rounds of 16 steps ----
  k_rnn<<<dim3(NBLK), 512, 0, stream>>>(w16_hi, w16_lo, h_hi, h_lo,
                                        z16_b, z16_lo, Part, flags);

  // ---- readout: p = h_127 @ Wph^T + b_p ----
  {
    Args a = {};
    a.seg[0] = { h_hi, wph_b, DHID, DHID, DHID };
    a.seg[1] = { h_lo, wph_b, DHID, DHID, DHID };
    a.n_seg = 2; a.n_iters = 2 * DHID / 64;
    a.bias = bp; a.out_hi = nullptr; a.out_lo = nullptr;
    a.out_f32 = (float*)d_out; a.ldo = NCLS;
    k_gemm<<<dim3(NCLS / 64, B_SZ / 32), 256, 0, stream>>>(a);
  }
}